// Round 9
// baseline (2748.647 us; speedup 1.0000x reference)
//
#include <hip/hip_runtime.h>
#include <hip/hip_bf16.h>

typedef __hip_bfloat16 bf16;
typedef short s8 __attribute__((ext_vector_type(8)));
typedef short sv4 __attribute__((ext_vector_type(4)));
typedef float f4 __attribute__((ext_vector_type(4)));

#define BETA 0.125f
#define EPS 1e-5f

__device__ __forceinline__ void gld16(const void* g, void* l){
    __builtin_amdgcn_global_load_lds(
        (const __attribute__((address_space(1))) void*)g,
        (__attribute__((address_space(3))) void*)l, 16, 0, 0);
}

// ---------- fused prologue converts: B1=[wq|wk|whop], we_, wd_, xb(padded) ----------
__global__ __launch_bounds__(256) void cvt_k(
    const float* __restrict__ wq, const float* __restrict__ wk, const float* __restrict__ whop,
    const float* __restrict__ wenc, const float* __restrict__ wdec, const float* __restrict__ x,
    bf16* __restrict__ B1, bf16* __restrict__ we, bf16* __restrict__ wd, bf16* __restrict__ xb)
{
    long i = (long)blockIdx.x*256 + threadIdx.x;
    if (i < 3538944){
        const float* s; long j = i;
        if (j < 589824) s = wq;
        else if (j < 1179648){ s = wk; j -= 589824; }
        else { s = whop; j -= 1179648; }
        B1[i] = __float2bfloat16(s[j]);
    } else if (i < 4128768){
        long j = i - 3538944; we[j] = __float2bfloat16(wenc[j]);
    } else if (i < 4718592){
        long j = i - 4128768; wd[j] = __float2bfloat16(wdec[j]);
    } else if (i < 9633792){
        long j = i - 4718592; long row = j / 768;
        xb[j] = (row < 6272) ? __float2bfloat16(x[j]) : __float2bfloat16(0.f);
    }
}

__global__ __launch_bounds__(256) void tr_k(const short* __restrict__ Bi, short* __restrict__ Bo){
    __shared__ short t[32][33];
    int i0 = blockIdx.x*32, j0 = blockIdx.y*32;
    int li = threadIdx.x & 31, lj = threadIdx.x >> 5;
    #pragma unroll
    for (int r=0;r<4;r++) t[lj+8*r][li] = Bi[(long)(i0+lj+8*r)*768 + j0+li];
    __syncthreads();
    #pragma unroll
    for (int r=0;r<4;r++) Bo[(long)(j0+lj+8*r)*4608 + i0+li] = t[li][lj+8*r];
}

__global__ __launch_bounds__(256) void cls_k(const float* __restrict__ cls, const float* __restrict__ pos,
                                             float* __restrict__ t){
    int i = blockIdx.x*256 + threadIdx.x;
    int b = i / 768, c = i % 768;
    t[((long)b*197)*768 + c] = cls[c] + pos[c];
}

// ---------- big MFMA GEMM: C = A[M,K] @ B[N,K]^T ----------
// LDS double-buffered 32-col panels (2 x 8KB per operand = 32KB total, same as before):
// loads for panel p+1 are issued immediately after the barrier of panel p, so the
// vmcnt(0) drain at the NEXT barrier happens after a full MFMA phase (latency overlap).
// Bank swizzle: quadrant q of row r at LDS quadrant (q+(r>>1))&3 (staging permutes source).
// Group-16 m-swizzle for per-XCD L2 A-reuse.
// MODE 0: C bf16, relu col>=relu0 | MODE 1: C fp32 store partial (z-offset zoff)
// MODE 2: encode epilogue | MODE 3: decode epilogue
template<int MODE>
__global__ __launch_bounds__(256) void big_gemm(
    const short* __restrict__ A, int lda,
    const short* __restrict__ B, int ldb,
    float* __restrict__ Cf, bf16* __restrict__ Cb, int ldc,
    int K, int Nn, int Nm, int relu0, long zoff,
    const float* __restrict__ bias, const float* __restrict__ pos)
{
    const int f = blockIdx.x;
    const int npg = 16*Nn;
    const int grp = f / npg;
    const int first_m = grp*16;
    const int gs = (Nm - first_m < 16) ? (Nm - first_m) : 16;
    const int rem = f % npg;
    const int bm = first_m + rem % gs;
    const int bn = rem / gs;

    __shared__ short lsA[8192];   // 2 halves x (128 rows x 32 cols)
    __shared__ short lsB[8192];
    const int tid = threadIdx.x;
    const int w = tid>>6, l = tid&63;
    const int m0 = bm*128, n0 = bn*128;
    const int srow = tid>>2;                       // 0..63
    const int qglob = ((tid&3) - (tid>>3)) & 3;    // swizzled source quadrant
    const int scol = qglob*8;
    int koff, Ks;
    if (MODE==1){ Ks = K>>1; koff = blockIdx.z * Ks; Cf += (size_t)blockIdx.z * zoff; }
    else        { Ks = K;    koff = 0; }
    const short* pa = A + (size_t)(m0+srow)*lda + koff + scol;
    const short* pb = B + (size_t)(n0+srow)*ldb + koff + scol;
    const size_t ra = 64*(size_t)lda, rb = 64*(size_t)ldb;
    const int wm = (w>>1)*64, wn = (w&1)*64;
    const int fr = l&15, fq = ((l>>4) + (fr>>1) & 3)*8;
    f4 acc[4][4] = {};
    const int nk = Ks>>5;     // 32-col panels

    // stage panel 0 into half 0
    gld16(pa,      lsA + w*512);
    gld16(pa + ra, lsA + 2048 + w*512);
    gld16(pb,      lsB + w*512);
    gld16(pb + rb, lsB + 2048 + w*512);

    #pragma unroll 2
    for (int p=0; p<nk; p++){
        const int half = p & 1;
        __syncthreads();                          // drains loads for panel p
        if (p+1 < nk){
            const int h2 = (p+1) & 1;
            const size_t ko = (size_t)(p+1)*32;
            gld16(pa + ko,      lsA + h2*4096 + w*512);
            gld16(pa + ko + ra, lsA + h2*4096 + 2048 + w*512);
            gld16(pb + ko,      lsB + h2*4096 + w*512);
            gld16(pb + ko + rb, lsB + h2*4096 + 2048 + w*512);
        }
        s8 af[4], bfr[4];
        #pragma unroll
        for (int i=0;i<4;i++) af[i]  = *(const s8*)(lsA + half*4096 + (wm+i*16+fr)*32 + fq);
        #pragma unroll
        for (int j=0;j<4;j++) bfr[j] = *(const s8*)(lsB + half*4096 + (wn+j*16+fr)*32 + fq);
        #pragma unroll
        for (int i=0;i<4;i++)
            #pragma unroll
            for (int j=0;j<4;j++)
                acc[i][j] = __builtin_amdgcn_mfma_f32_16x16x32_bf16(af[i], bfr[j], acc[i][j], 0,0,0);
    }

    const int er = (l>>4)*4;
    const int ec = l&15;
    #pragma unroll
    for (int i=0;i<4;i++){
        #pragma unroll
        for (int j=0;j<4;j++){
            int gr0 = m0 + wm + i*16 + er;
            int gc  = n0 + wn + j*16 + ec;
            #pragma unroll
            for (int r=0;r<4;r++){
                float v = acc[i][j][r];
                int gr = gr0 + r;
                if (MODE==0){
                    if (gc >= relu0) v = v>0.f ? v : 0.f;
                    Cb[(size_t)gr*ldc + gc] = __float2bfloat16(v);
                } else if (MODE==1){
                    Cf[(size_t)gr*ldc + gc] = v;
                } else if (MODE==2){
                    if (gr < 6272){
                        int b = gr/196, n = gr%196;
                        Cf[((size_t)b*197 + n + 1)*768 + gc] = v + bias[gc] + pos[(long)(n+1)*768+gc];
                    }
                } else {
                    if (gr < 6272) Cf[(size_t)gr*ldc + gc] = v + bias[gc];
                }
            }
        }
    }
}

// ---------- fused attention per (b,h): builds qT/kT in LDS (pack_k folded in) ----------
// LDS map (shorts): qTl [64][280] @0, kTl [64][280] @17920,
//                   Pl [64][232] @35840, Ptl [208][72] @50688  (total 131.3 KB)
// phase-A scratch tq/tk overlap the Pl region.
__global__ __launch_bounds__(256) void attn_k(short* __restrict__ qkh)
{
    __shared__ short sm[65664];
    short* qTl = sm;
    short* kTl = sm + 17920;
    short* Pl  = sm + 35840;
    short* Ptl = sm + 50688;
    short* tq  = sm + 35840;      // scratch (phase A only)
    short* tk  = sm + 40000;

    const int bh = blockIdx.x, b = bh/12, h = bh%12;
    const int tid = threadIdx.x, w = tid>>6, l = tid&63;
    const int lr = l&15, lq = l>>4;
    const size_t qcol = (size_t)h*64, kcol = 768 + qcol;
    const size_t rbase = (size_t)b*197*4608;

    // ---- phase A: build qTl/kTl (zero-padded to m=256) via LDS transpose ----
    for (int mc=0; mc<256; mc+=64){
        #pragma unroll
        for (int e=0;e<16;e++){
            int i = tid + e*256; int r = i>>6, c = i&63;
            int mg = mc + r;
            short vq = 0, vk = 0;
            if (mg < 197){
                size_t base = rbase + (size_t)mg*4608 + qcol + c;
                vq = qkh[base]; vk = qkh[base+768];
            }
            tq[r*65+c] = vq; tk[r*65+c] = vk;
        }
        __syncthreads();
        #pragma unroll
        for (int e=0;e<16;e++){
            int i = tid + e*256; int zr = i>>6, cm = i&63;
            qTl[zr*280 + mc + cm] = tq[cm*65+zr];
            kTl[zr*280 + mc + cm] = tk[cm*65+zr];
        }
        __syncthreads();
    }
    // zero P pad cols 208..223 (read by aq k-step 6)
    for (int i=tid; i<64*16; i+=256){ int r=i>>4, c=208+(i&15); Pl[r*232+c]=0; }

    f4 ak[13];
    #pragma unroll
    for (int t=0;t<13;t++) ak[t] = (f4){0.f,0.f,0.f,0.f};

    for (int iter=0; iter<4; iter++){
        const int m0 = iter*64;
        f4 S[13];
        #pragma unroll
        for (int t=0;t<13;t++) S[t] = (f4){0.f,0.f,0.f,0.f};
        const int mrow = m0 + w*16 + lr;
        #pragma unroll
        for (int ks=0; ks<2; ks++){
            s8 af = *(const s8*)(qkh + rbase + (size_t)mrow*4608 + qcol + ks*32 + lq*8);
            #pragma unroll
            for (int t=0;t<13;t++){
                s8 bf = *(const s8*)(qkh + rbase + (size_t)(t*16+lr)*4608 + kcol + ks*32 + lq*8);
                S[t] = __builtin_amdgcn_mfma_f32_16x16x32_bf16(af, bf, S[t], 0,0,0);
            }
        }
        __syncthreads();
        const int mbase = w*16 + lq*4;
        #pragma unroll
        for (int r=0;r<4;r++){
            float mx = -1e30f;
            #pragma unroll
            for (int t=0;t<13;t++){
                float v = S[t][r]*BETA;
                if (t==12 && lr>=5) v = -1e30f;
                S[t][r] = v;
                mx = fmaxf(mx, v);
            }
            mx = fmaxf(mx, __shfl_xor(mx,1,64)); mx = fmaxf(mx, __shfl_xor(mx,2,64));
            mx = fmaxf(mx, __shfl_xor(mx,4,64)); mx = fmaxf(mx, __shfl_xor(mx,8,64));
            float sm_ = 0.f;
            #pragma unroll
            for (int t=0;t<13;t++){ float e = __expf(S[t][r]-mx); S[t][r]=e; sm_+=e; }
            sm_ += __shfl_xor(sm_,1,64); sm_ += __shfl_xor(sm_,2,64);
            sm_ += __shfl_xor(sm_,4,64); sm_ += __shfl_xor(sm_,8,64);
            float inv = 1.f/sm_;
            bool valid = (m0 + mbase + r) < 197;
            #pragma unroll
            for (int t=0;t<13;t++) S[t][r] = valid ? S[t][r]*inv : 0.f;
        }
        #pragma unroll
        for (int t=0;t<13;t++){
            int c = t*16 + lr;
            short pb[4];
            #pragma unroll
            for (int r=0;r<4;r++){
                bf16 bv = __float2bfloat16(S[t][r]);
                pb[r] = *(short*)&bv;
                Pl[(mbase+r)*232 + c] = pb[r];
            }
            *(sv4*)(Ptl + c*72 + mbase) = (sv4){pb[0],pb[1],pb[2],pb[3]};
        }
        __syncthreads();
        // aq^T = kT x P
        f4 aq[4];
        #pragma unroll
        for (int t=0;t<4;t++) aq[t] = (f4){0.f,0.f,0.f,0.f};
        #pragma unroll
        for (int ks=0; ks<7; ks++){
            s8 af = *(const s8*)(kTl + (w*16+lr)*280 + ks*32 + lq*8);
            #pragma unroll
            for (int mt=0;mt<4;mt++){
                s8 bf = *(const s8*)(Pl + (mt*16+lr)*232 + ks*32 + lq*8);
                aq[mt] = __builtin_amdgcn_mfma_f32_16x16x32_bf16(af, bf, aq[mt], 0,0,0);
            }
        }
        #pragma unroll
        for (int mt=0;mt<4;mt++){
            int mg = m0 + mt*16 + lr;
            if (mg < 197){
                sv4 pv;
                #pragma unroll
                for (int r=0;r<4;r++){ bf16 bv=__float2bfloat16(aq[mt][r]); pv[r]=*(short*)&bv; }
                *(sv4*)(qkh + rbase + (size_t)mg*4608 + qcol + w*16 + lq*4) = pv;
            }
        }
        // ak += Pt x qT
        #pragma unroll
        for (int ks=0; ks<2; ks++){
            s8 bf = *(const s8*)(qTl + (w*16+lr)*280 + m0 + ks*32 + lq*8);
            #pragma unroll
            for (int t=0;t<13;t++){
                s8 af = *(const s8*)(Ptl + (t*16+lr)*72 + ks*32 + lq*8);
                ak[t] = __builtin_amdgcn_mfma_f32_16x16x32_bf16(af, bf, ak[t], 0,0,0);
            }
        }
    }
    #pragma unroll
    for (int t=0;t<13;t++){
        #pragma unroll
        for (int r=0;r<4;r++){
            int n = t*16 + lq*4 + r;
            if (n < 197)
                *(bf16*)(qkh + rbase + (size_t)n*4608 + kcol + w*16 + lr) = __float2bfloat16(ak[t][r]);
        }
    }
}

// ---------- LN (float4; folds split-K partials into t first) ----------
__global__ __launch_bounds__(256) void ln_k(
    float* __restrict__ in, bf16* __restrict__ out,
    const float* __restrict__ p0, const float* __restrict__ p1,
    const float* __restrict__ scale, const float* __restrict__ bias,
    int scalar_scale, int rowmap, int addp, int writet)
{
    int r = blockIdx.x;
    long src = rowmap ? ((long)(r/196)*197 + r%196 + 1) : (long)r;
    float4* xr = (float4*)(in + src*768);
    int tid = threadIdx.x;
    float4 v = {0.f,0.f,0.f,0.f};
    if (tid < 192){
        v = xr[tid];
        if (addp){
            float4 a = ((const float4*)(p0 + src*768))[tid];
            float4 b = ((const float4*)(p1 + src*768))[tid];
            v.x += a.x+b.x; v.y += a.y+b.y; v.z += a.z+b.z; v.w += a.w+b.w;
            if (writet) xr[tid] = v;
        }
    }
    __shared__ float red[4];
    float s = v.x+v.y+v.z+v.w;
    #pragma unroll
    for (int o=1;o<64;o<<=1) s += __shfl_xor(s, o, 64);
    if ((tid&63)==0) red[tid>>6] = s;
    __syncthreads();
    float mu = (red[0]+red[1]+red[2]+red[3]) * (1.f/768.f);
    float d0=v.x-mu, d1=v.y-mu, d2=v.z-mu, d3=v.w-mu;
    float q = d0*d0 + d1*d1 + d2*d2 + d3*d3;
    if (tid >= 192) q = 0.f;
    #pragma unroll
    for (int o=1;o<64;o<<=1) q += __shfl_xor(q, o, 64);
    __syncthreads();
    if ((tid&63)==0) red[tid>>6] = q;
    __syncthreads();
    float ms = (red[0]+red[1]+red[2]+red[3]) * (1.f/768.f);
    float inv = rsqrtf(ms + EPS);
    if (tid < 192){
        int c = tid*4;
        float s0 = scalar_scale ? scale[0] : scale[c];
        float s1 = scalar_scale ? s0 : scale[c+1];
        float s2 = scalar_scale ? s0 : scale[c+2];
        float s3 = scalar_scale ? s0 : scale[c+3];
        bf16 b0 = __float2bfloat16(d0*inv*s0 + bias[c]);
        bf16 b1 = __float2bfloat16(d1*inv*s1 + bias[c+1]);
        bf16 b2 = __float2bfloat16(d2*inv*s2 + bias[c+2]);
        bf16 b3 = __float2bfloat16(d3*inv*s3 + bias[c+3]);
        sv4 pv = { *(short*)&b0, *(short*)&b1, *(short*)&b2, *(short*)&b3 };
        ((sv4*)(out + (long)r*768))[tid] = pv;
    }
}

extern "C" void kernel_launch(void* const* d_in, const int* in_sizes, int n_in,
                              void* d_out, int out_size, void* d_ws, size_t ws_size,
                              hipStream_t stream) {
    const float* x       = (const float*)d_in[0];
    const float* w_enc   = (const float*)d_in[1];
    const float* b_enc   = (const float*)d_in[2];
    const float* cls_tok = (const float*)d_in[3];
    const float* pos     = (const float*)d_in[4];
    const float* eln_g   = (const float*)d_in[5];
    const float* eln_b   = (const float*)d_in[6];
    const float* wq      = (const float*)d_in[7];
    const float* wk      = (const float*)d_in[8];
    const float* w_hop   = (const float*)d_in[9];
    const float* dln_w   = (const float*)d_in[10];
    const float* dln_b   = (const float*)d_in[11];
    const float* w_dec   = (const float*)d_in[12];
    const float* b_dec   = (const float*)d_in[13];
    float* out = (float*)d_out;

    float* t_  = (float*)d_ws;                    // [6400,768] fp32
    bf16* g_   = (bf16*)(t_ + 6400L*768);         // [6400,768]
    bf16* qkh  = g_ + 6400L*768;                  // [6400,4608] = q|k|h (aq|ak overwrite q|k)
    float* p0  = (float*)(qkh + 6400L*4608);      // [6400,768] split-K partial z=0
    float* p1  = p0 + 6400L*768;                  // [6400,768] split-K partial z=1
    bf16* B1   = (bf16*)(p1 + 6400L*768);         // [4608,768]  wq|wk|whop
    bf16* B2   = B1 + 4608L*768;                  // [768,4608]  = B1^T
    bf16* we_  = B2 + 768L*4608;                  // [768,768]
    bf16* wd_  = we_ + 768L*768;                  // [768,768]

    dim3 blk(256);
    const long ZOFF = 6400L*768;

    cvt_k<<<dim3(37632), blk, 0, stream>>>(wq, wk, w_hop, w_enc, w_dec, x,
                                           B1, we_, wd_, g_);
    tr_k<<<dim3(144,24), blk, 0, stream>>>((const short*)B1, (short*)B2);

    cls_k<<<dim3(96), blk, 0, stream>>>(cls_tok, pos, t_);
    big_gemm<2><<<dim3(300), blk, 0, stream>>>((const short*)g_, 768, (const short*)we_, 768,
                                               t_, nullptr, 768, 768, 6, 50, 0, 0, b_enc, pos);

    for (int step=0; step<12; step++){
        ln_k<<<dim3(6304), blk, 0, stream>>>(t_, g_, p0, p1, eln_g, eln_b, 1, 0, step>0, 1);
        big_gemm<0><<<dim3(1800), blk, 0, stream>>>((const short*)g_, 768, (const short*)B1, 768,
                                                    nullptr, qkh, 4608, 768, 36, 50, 1536, 0, nullptr, nullptr);
        attn_k<<<dim3(384), blk, 0, stream>>>((short*)qkh);
        big_gemm<1><<<dim3(300,1,2), blk, 0, stream>>>((const short*)qkh, 4608, (const short*)B2, 4608,
                                                       p0, nullptr, 768, 4608, 6, 50, 0, ZOFF, nullptr, nullptr);
    }

    ln_k<<<dim3(6272), blk, 0, stream>>>(t_, g_, p0, p1, dln_w, dln_b, 0, 1, 1, 0);
    big_gemm<3><<<dim3(300), blk, 0, stream>>>((const short*)g_, 768, (const short*)wd_, 768,
                                               out, nullptr, 768, 768, 6, 50, 0, 0, b_dec, nullptr);
}